// Round 1
// baseline (3272.339 us; speedup 1.0000x reference)
//
#include <hip/hip_runtime.h>
#include <math.h>

#define NU 100000
#define NB 50000
#define NI 100000
#define D 64
#define NLAYER 3
#define NNZ 2000000
#define BATCH 8192
#define LEAKY 0.2f
#define N_UB (NU + NB)   // 150000
#define N_IU (NI + NU)   // 200000

// ---------------------------------------------------------------------------
// concat emb_u|emb_b -> x, and accumulate l2 = 0.5*(sum u^2 + sum b^2)/NU
// one float4 per thread; exact grid division (N_UB*D/4 = 2.4M)
// ---------------------------------------------------------------------------
__global__ __launch_bounds__(256) void concat_l2_kernel(
    const float* __restrict__ emb_u, const float* __restrict__ emb_b,
    float* __restrict__ x, float* __restrict__ out) {
  int i = blockIdx.x * blockDim.x + threadIdx.x;  // float4 index
  const int total4 = (N_UB * D) / 4;
  float sq = 0.f;
  if (i < total4) {
    float4 v;
    if (i < (NU * D) / 4)
      v = ((const float4*)emb_u)[i];
    else
      v = ((const float4*)emb_b)[i - (NU * D) / 4];
    ((float4*)x)[i] = v;
    sq = v.x * v.x + v.y * v.y + v.z * v.z + v.w * v.w;
  }
  // wave-64 reduce, one atomic per wave
  for (int off = 32; off; off >>= 1) sq += __shfl_down(sq, off);
  if ((threadIdx.x & 63) == 0 && sq != 0.f)
    atomicAdd(&out[1], sq * (0.5f / (float)NU));
}

// ---------------------------------------------------------------------------
// SpMM pass 1: y[cols[e]][d] += vals[e] * x[rows[e]][d]
// one wave per edge, lane = dimension d
// ---------------------------------------------------------------------------
__global__ __launch_bounds__(256) void spmm_xy_kernel(
    const float* __restrict__ vals, const int* __restrict__ rows,
    const int* __restrict__ cols, const float* __restrict__ x,
    float* __restrict__ y) {
  int e = blockIdx.x * (blockDim.x >> 6) + (threadIdx.x >> 6);
  if (e >= NNZ) return;
  int lane = threadIdx.x & 63;
  int r = rows[e];
  int c = cols[e];
  float v = vals[e];
  atomicAdd(&y[(size_t)c * D + lane], v * x[(size_t)r * D + lane]);
}

// ---------------------------------------------------------------------------
// SpMM pass 2 with fused filter scale:
//   x[rows[e]][d] += vals[e] * leaky(filt_l[cols[e]]) * y[cols[e]][d]
// ---------------------------------------------------------------------------
__global__ __launch_bounds__(256) void spmm_yx_kernel(
    const float* __restrict__ vals, const int* __restrict__ rows,
    const int* __restrict__ cols, const float* __restrict__ y,
    const float* __restrict__ filt_l, float* __restrict__ x) {
  int e = blockIdx.x * (blockDim.x >> 6) + (threadIdx.x >> 6);
  if (e >= NNZ) return;
  int lane = threadIdx.x & 63;
  int r = rows[e];
  int c = cols[e];
  float fw = filt_l[c];
  float f = fw > 0.f ? fw : LEAKY * fw;
  float v = vals[e] * f;
  atomicAdd(&x[(size_t)r * D + lane], v * y[(size_t)c * D + lane]);
}

// ---------------------------------------------------------------------------
// gather-accumulate the rows the loss needs:
//   uacc[i] += x[u_idx[i]]          (i in [0,BATCH))
//   bacc[j] += x[NU + b_idx[j]]     (j in [0,2*BATCH))
// one wave per row; output rows unique -> plain adds
// ---------------------------------------------------------------------------
__global__ __launch_bounds__(256) void gather_acc_kernel(
    const float* __restrict__ x, const int* __restrict__ u_idx,
    const int* __restrict__ b_idx, float* __restrict__ uacc,
    float* __restrict__ bacc) {
  int r = blockIdx.x * (blockDim.x >> 6) + (threadIdx.x >> 6);
  int lane = threadIdx.x & 63;
  if (r < BATCH) {
    int src = u_idx[r];
    uacc[(size_t)r * D + lane] += x[(size_t)src * D + lane];
  } else if (r < 3 * BATCH) {
    int rb = r - BATCH;  // flat (i,k) index into b_idx / bacc
    int src = NU + b_idx[rb];
    bacc[(size_t)rb * D + lane] += x[(size_t)src * D + lane];
  }
}

// ---------------------------------------------------------------------------
// loss: rating[i,k] = dot(final_b[i,k], final_u[i]); final = acc/4 so the
// product carries 1/16. z = dot(u, b1-b0); loss = mean softplus(z).
// one wave per batch element.
// ---------------------------------------------------------------------------
__global__ __launch_bounds__(256) void loss_kernel(
    const float* __restrict__ uacc, const float* __restrict__ bacc,
    float* __restrict__ out) {
  int i = blockIdx.x * (blockDim.x >> 6) + (threadIdx.x >> 6);
  if (i >= BATCH) return;
  int lane = threadIdx.x & 63;
  float u = uacc[(size_t)i * D + lane];
  float b0 = bacc[(size_t)(i * 2 + 0) * D + lane];
  float b1 = bacc[(size_t)(i * 2 + 1) * D + lane];
  float t = u * (b1 - b0) * (1.0f / 16.0f);
  for (int off = 32; off; off >>= 1) t += __shfl_down(t, off);
  if (lane == 0) {
    float z = t;
    // numerically stable softplus
    float sp = z > 0.f ? z + log1pf(expf(-z)) : log1pf(expf(z));
    atomicAdd(&out[0], sp * (1.0f / (float)BATCH));
  }
}

extern "C" void kernel_launch(void* const* d_in, const int* in_sizes, int n_in,
                              void* d_out, int out_size, void* d_ws,
                              size_t ws_size, hipStream_t stream) {
  const float* emb_u = (const float*)d_in[0];
  const float* emb_b = (const float*)d_in[1];
  const float* filter_w = (const float*)d_in[2];
  const float* vals = (const float*)d_in[3];
  const int* rows = (const int*)d_in[4];
  const int* cols = (const int*)d_in[5];
  const int* u_idx = (const int*)d_in[6];
  const int* b_idx = (const int*)d_in[7];
  float* out = (float*)d_out;

  // workspace layout (floats): xA | y | uacc | bacc   (~96 MB total)
  float* xA = (float*)d_ws;
  float* y = xA + (size_t)N_UB * D;
  float* uacc = y + (size_t)N_IU * D;
  float* bacc = uacc + (size_t)BATCH * D;

  hipMemsetAsync(out, 0, 2 * sizeof(float), stream);
  hipMemsetAsync(uacc, 0, (size_t)(BATCH * D + BATCH * 2 * D) * sizeof(float),
                 stream);

  // x0 = concat(emb_u, emb_b); l2 accumulated into out[1]
  int total4 = (N_UB * D) / 4;
  concat_l2_kernel<<<(total4 + 255) / 256, 256, 0, stream>>>(emb_u, emb_b, xA,
                                                             out);
  // acc contribution of x0 at the gathered rows
  gather_acc_kernel<<<(3 * BATCH + 3) / 4, 256, 0, stream>>>(xA, u_idx, b_idx,
                                                             uacc, bacc);

  const int spmm_blocks = (NNZ + 3) / 4;
  for (int l = 0; l < NLAYER; ++l) {
    hipMemsetAsync(y, 0, (size_t)N_IU * D * sizeof(float), stream);
    spmm_xy_kernel<<<spmm_blocks, 256, 0, stream>>>(vals, rows, cols, xA, y);
    hipMemsetAsync(xA, 0, (size_t)N_UB * D * sizeof(float), stream);
    spmm_yx_kernel<<<spmm_blocks, 256, 0, stream>>>(
        vals, rows, cols, y, filter_w + (size_t)l * N_IU, xA);
    gather_acc_kernel<<<(3 * BATCH + 3) / 4, 256, 0, stream>>>(
        xA, u_idx, b_idx, uacc, bacc);
  }

  loss_kernel<<<(BATCH + 3) / 4, 256, 0, stream>>>(uacc, bacc, out);
}

// Round 2
// 1322.561 us; speedup vs baseline: 2.4742x; 2.4742x over previous
//
#include <hip/hip_runtime.h>
#include <math.h>

#define NU 100000
#define NB 50000
#define NI 100000
#define D 64
#define NLAYER 3
#define NNZ 2000000
#define BATCH 8192
#define LEAKY 0.2f
#define N_UB (NU + NB)   // 150000
#define N_IU (NI + NU)   // 200000

// ---------------------------------------------------------------------------
// concat emb_u|emb_b -> x, and accumulate l2 = 0.5*(sum u^2 + sum b^2)/NU
// grid-stride (1024 blocks); block-level reduce -> ONE atomic per block.
// ---------------------------------------------------------------------------
__global__ __launch_bounds__(256) void concat_l2_kernel(
    const float* __restrict__ emb_u, const float* __restrict__ emb_b,
    float* __restrict__ x, float* __restrict__ out) {
  const int total4 = (N_UB * D) / 4;
  const int nu4 = (NU * D) / 4;
  float sq = 0.f;
  for (int i = blockIdx.x * blockDim.x + threadIdx.x; i < total4;
       i += gridDim.x * blockDim.x) {
    float4 v = (i < nu4) ? ((const float4*)emb_u)[i]
                         : ((const float4*)emb_b)[i - nu4];
    ((float4*)x)[i] = v;
    sq += v.x * v.x + v.y * v.y + v.z * v.z + v.w * v.w;
  }
  for (int off = 32; off; off >>= 1) sq += __shfl_down(sq, off);
  __shared__ float wsum[4];
  if ((threadIdx.x & 63) == 0) wsum[threadIdx.x >> 6] = sq;
  __syncthreads();
  if (threadIdx.x == 0) {
    float s = wsum[0] + wsum[1] + wsum[2] + wsum[3];
    atomicAdd(&out[1], s * (0.5f / (float)NU));
  }
}

// ---------------------------------------------------------------------------
// CSR build: histogram both sides in one pass
// ---------------------------------------------------------------------------
__global__ __launch_bounds__(256) void hist_kernel(
    const int* __restrict__ rows, const int* __restrict__ cols,
    int* __restrict__ cntr, int* __restrict__ cntc) {
  int e = blockIdx.x * blockDim.x + threadIdx.x;
  if (e >= NNZ) return;
  atomicAdd(&cntr[rows[e]], 1);
  atomicAdd(&cntc[cols[e]], 1);
}

// per-block exclusive scan (1024 elems/block); block totals to blktot
__global__ __launch_bounds__(1024) void scan_block_kernel(
    const int* __restrict__ in, int* __restrict__ out, int* __restrict__ blktot,
    int n) {
  __shared__ int s[1024];
  int tid = threadIdx.x;
  int i = blockIdx.x * 1024 + tid;
  int v = (i < n) ? in[i] : 0;
  s[tid] = v;
  __syncthreads();
  for (int off = 1; off < 1024; off <<= 1) {
    int t = (tid >= off) ? s[tid - off] : 0;
    __syncthreads();
    s[tid] += t;
    __syncthreads();
  }
  if (i < n) out[i] = s[tid] - v;  // exclusive
  if (tid == 1023) blktot[blockIdx.x] = s[1023];
}

// single-block exclusive scan of block totals (nb <= 1024)
__global__ __launch_bounds__(1024) void scan_top_kernel(int* __restrict__ b,
                                                        int nb) {
  __shared__ int s[1024];
  int tid = threadIdx.x;
  int v = (tid < nb) ? b[tid] : 0;
  s[tid] = v;
  __syncthreads();
  for (int off = 1; off < 1024; off <<= 1) {
    int t = (tid >= off) ? s[tid - off] : 0;
    __syncthreads();
    s[tid] += t;
    __syncthreads();
  }
  if (tid < nb) b[tid] = s[tid] - v;
}

// add block offsets; init scatter cursors; set ptr[n]=total
__global__ __launch_bounds__(1024) void add_off_kernel(
    int* __restrict__ out, const int* __restrict__ blktot, int* __restrict__ cur,
    int n, int total) {
  int i = blockIdx.x * 1024 + threadIdx.x;
  if (i < n) {
    int p = out[i] + blktot[blockIdx.x];
    out[i] = p;
    cur[i] = p;
  }
  if (i == 0) out[n] = total;
}

// scatter edges into both CSR orderings; record packed {partner, val}
__global__ __launch_bounds__(256) void scatter_kernel(
    const float* __restrict__ vals, const int* __restrict__ rows,
    const int* __restrict__ cols, int* __restrict__ curr, int* __restrict__ curc,
    int2* __restrict__ er, int2* __restrict__ ec) {
  int e = blockIdx.x * blockDim.x + threadIdx.x;
  if (e >= NNZ) return;
  int r = rows[e];
  int c = cols[e];
  int v = __float_as_int(vals[e]);
  int p = atomicAdd(&curc[c], 1);
  ec[p] = make_int2(r, v);
  int q = atomicAdd(&curr[r], 1);
  er[q] = make_int2(c, v);
}

// ---------------------------------------------------------------------------
// pass 1 (CSR by col): y[c] = leaky(filt[c]) * sum_e val*x[src]; wave per c
// ---------------------------------------------------------------------------
__global__ __launch_bounds__(256) void spmm_col_kernel(
    const int* __restrict__ ptrc, const int2* __restrict__ ec,
    const float* __restrict__ x, const float* __restrict__ filt,
    float* __restrict__ y) {
  int c = blockIdx.x * 4 + (threadIdx.x >> 6);
  if (c >= N_IU) return;
  int lane = threadIdx.x & 63;
  int e = ptrc[c], e2 = ptrc[c + 1];
  float acc = 0.f;
  for (; e + 2 <= e2; e += 2) {
    int2 p0 = ec[e];
    int2 p1 = ec[e + 1];
    acc += __int_as_float(p0.y) * x[(size_t)p0.x * D + lane];
    acc += __int_as_float(p1.y) * x[(size_t)p1.x * D + lane];
  }
  if (e < e2) {
    int2 p = ec[e];
    acc += __int_as_float(p.y) * x[(size_t)p.x * D + lane];
  }
  float fw = filt[c];
  float f = fw > 0.f ? fw : LEAKY * fw;
  y[(size_t)c * D + lane] = acc * f;
}

// ---------------------------------------------------------------------------
// pass 2 (CSR by row): x[r] = sum_e val*y[src]; wave per r
// ---------------------------------------------------------------------------
__global__ __launch_bounds__(256) void spmm_row_kernel(
    const int* __restrict__ ptrr, const int2* __restrict__ er,
    const float* __restrict__ y, float* __restrict__ x) {
  int r = blockIdx.x * 4 + (threadIdx.x >> 6);
  if (r >= N_UB) return;
  int lane = threadIdx.x & 63;
  int e = ptrr[r], e2 = ptrr[r + 1];
  float acc = 0.f;
  for (; e + 2 <= e2; e += 2) {
    int2 p0 = er[e];
    int2 p1 = er[e + 1];
    acc += __int_as_float(p0.y) * y[(size_t)p0.x * D + lane];
    acc += __int_as_float(p1.y) * y[(size_t)p1.x * D + lane];
  }
  if (e < e2) {
    int2 p = er[e];
    acc += __int_as_float(p.y) * y[(size_t)p.x * D + lane];
  }
  x[(size_t)r * D + lane] = acc;
}

// ---------------------------------------------------------------------------
// last layer: pass 2 evaluated ONLY at gathered rows, accumulated directly
// into uacc/bacc. wave per gathered slot.
// ---------------------------------------------------------------------------
__global__ __launch_bounds__(256) void spmm_gather_last_kernel(
    const int* __restrict__ ptrr, const int2* __restrict__ er,
    const float* __restrict__ y, const int* __restrict__ u_idx,
    const int* __restrict__ b_idx, float* __restrict__ uacc,
    float* __restrict__ bacc) {
  int i = blockIdx.x * 4 + (threadIdx.x >> 6);
  if (i >= 3 * BATCH) return;
  int lane = threadIdx.x & 63;
  int row;
  float* dst;
  if (i < BATCH) {
    row = u_idx[i];
    dst = &uacc[(size_t)i * D];
  } else {
    int j = i - BATCH;
    row = NU + b_idx[j];
    dst = &bacc[(size_t)j * D];
  }
  int e = ptrr[row], e2 = ptrr[row + 1];
  float acc = 0.f;
  for (; e + 2 <= e2; e += 2) {
    int2 p0 = er[e];
    int2 p1 = er[e + 1];
    acc += __int_as_float(p0.y) * y[(size_t)p0.x * D + lane];
    acc += __int_as_float(p1.y) * y[(size_t)p1.x * D + lane];
  }
  if (e < e2) {
    int2 p = er[e];
    acc += __int_as_float(p.y) * y[(size_t)p.x * D + lane];
  }
  dst[lane] += acc;
}

// ---------------------------------------------------------------------------
// gather-accumulate rows the loss needs (intermediate layers)
// ---------------------------------------------------------------------------
__global__ __launch_bounds__(256) void gather_acc_kernel(
    const float* __restrict__ x, const int* __restrict__ u_idx,
    const int* __restrict__ b_idx, float* __restrict__ uacc,
    float* __restrict__ bacc) {
  int r = blockIdx.x * 4 + (threadIdx.x >> 6);
  int lane = threadIdx.x & 63;
  if (r < BATCH) {
    int src = u_idx[r];
    uacc[(size_t)r * D + lane] += x[(size_t)src * D + lane];
  } else if (r < 3 * BATCH) {
    int rb = r - BATCH;
    int src = NU + b_idx[rb];
    bacc[(size_t)rb * D + lane] += x[(size_t)src * D + lane];
  }
}

// ---------------------------------------------------------------------------
// loss: z = dot(u, b1-b0)/16; loss = mean softplus(z). wave per batch elem.
// ---------------------------------------------------------------------------
__global__ __launch_bounds__(256) void loss_kernel(
    const float* __restrict__ uacc, const float* __restrict__ bacc,
    float* __restrict__ out) {
  int i = blockIdx.x * 4 + (threadIdx.x >> 6);
  if (i >= BATCH) return;
  int lane = threadIdx.x & 63;
  float u = uacc[(size_t)i * D + lane];
  float b0 = bacc[(size_t)(i * 2 + 0) * D + lane];
  float b1 = bacc[(size_t)(i * 2 + 1) * D + lane];
  float t = u * (b1 - b0) * (1.0f / 16.0f);
  for (int off = 32; off; off >>= 1) t += __shfl_down(t, off);
  if (lane == 0) {
    float z = t;
    float sp = z > 0.f ? z + log1pf(expf(-z)) : log1pf(expf(z));
    atomicAdd(&out[0], sp * (1.0f / (float)BATCH));
  }
}

extern "C" void kernel_launch(void* const* d_in, const int* in_sizes, int n_in,
                              void* d_out, int out_size, void* d_ws,
                              size_t ws_size, hipStream_t stream) {
  const float* emb_u = (const float*)d_in[0];
  const float* emb_b = (const float*)d_in[1];
  const float* filter_w = (const float*)d_in[2];
  const float* vals = (const float*)d_in[3];
  const int* rows = (const int*)d_in[4];
  const int* cols = (const int*)d_in[5];
  const int* u_idx = (const int*)d_in[6];
  const int* b_idx = (const int*)d_in[7];
  float* out = (float*)d_out;

  // workspace layout (4B units)
  float* xA = (float*)d_ws;                         // N_UB*D
  float* y = xA + (size_t)N_UB * D;                 // N_IU*D
  float* uacc = y + (size_t)N_IU * D;               // BATCH*D
  float* bacc = uacc + (size_t)BATCH * D;           // 2*BATCH*D
  int2* ec = (int2*)(bacc + (size_t)2 * BATCH * D); // NNZ int2 (8B-aligned)
  int2* er = ec + NNZ;                              // NNZ int2
  int* ptrc = (int*)(er + NNZ);                     // N_IU+1
  int* ptrr = ptrc + (N_IU + 1);                    // N_UB+1
  int* curc = ptrr + (N_UB + 1);                    // N_IU (also hist counts)
  int* curr = curc + N_IU;                          // N_UB
  int* blktot = curr + N_UB;                        // 1024

  hipMemsetAsync(out, 0, 2 * sizeof(float), stream);
  hipMemsetAsync(uacc, 0, (size_t)3 * BATCH * D * sizeof(float), stream);
  hipMemsetAsync(curc, 0, (size_t)N_IU * sizeof(int), stream);
  hipMemsetAsync(curr, 0, (size_t)N_UB * sizeof(int), stream);

  // x0 = concat; l2 into out[1]
  concat_l2_kernel<<<1024, 256, 0, stream>>>(emb_u, emb_b, xA, out);
  // acc contribution of x0
  gather_acc_kernel<<<(3 * BATCH + 3) / 4, 256, 0, stream>>>(xA, u_idx, b_idx,
                                                             uacc, bacc);

  // ---- build CSRs (by col and by row) ----
  hist_kernel<<<(NNZ + 255) / 256, 256, 0, stream>>>(rows, cols, curr, curc);
  {
    int nb = (N_IU + 1023) / 1024;  // 196
    scan_block_kernel<<<nb, 1024, 0, stream>>>(curc, ptrc, blktot, N_IU);
    scan_top_kernel<<<1, 1024, 0, stream>>>(blktot, nb);
    add_off_kernel<<<nb, 1024, 0, stream>>>(ptrc, blktot, curc, N_IU, NNZ);
  }
  {
    int nb = (N_UB + 1023) / 1024;  // 147
    scan_block_kernel<<<nb, 1024, 0, stream>>>(curr, ptrr, blktot, N_UB);
    scan_top_kernel<<<1, 1024, 0, stream>>>(blktot, nb);
    add_off_kernel<<<nb, 1024, 0, stream>>>(ptrr, blktot, curr, N_UB, NNZ);
  }
  scatter_kernel<<<(NNZ + 255) / 256, 256, 0, stream>>>(vals, rows, cols, curr,
                                                        curc, er, ec);

  // ---- 3 layers ----
  for (int l = 0; l < NLAYER; ++l) {
    spmm_col_kernel<<<(N_IU + 3) / 4, 256, 0, stream>>>(
        ptrc, ec, xA, filter_w + (size_t)l * N_IU, y);
    if (l < NLAYER - 1) {
      spmm_row_kernel<<<(N_UB + 3) / 4, 256, 0, stream>>>(ptrr, er, y, xA);
      gather_acc_kernel<<<(3 * BATCH + 3) / 4, 256, 0, stream>>>(
          xA, u_idx, b_idx, uacc, bacc);
    } else {
      spmm_gather_last_kernel<<<(3 * BATCH + 3) / 4, 256, 0, stream>>>(
          ptrr, er, y, u_idx, b_idx, uacc, bacc);
    }
  }

  loss_kernel<<<(BATCH + 3) / 4, 256, 0, stream>>>(uacc, bacc, out);
}

// Round 3
// 880.415 us; speedup vs baseline: 3.7168x; 1.5022x over previous
//
#include <hip/hip_runtime.h>
#include <hip/hip_fp16.h>
#include <math.h>

#define NU 100000
#define NB 50000
#define NI 100000
#define D 64
#define NLAYER 3
#define NNZ 2000000
#define BATCH 8192
#define LEAKY 0.2f
#define N_UB (NU + NB)   // 150000
#define N_IU (NI + NU)   // 200000

#define SBIN 15          // scatter bin = 32768 nodes
#define NSWEEP 7         // covers max(N_IU, N_UB) = 200000 < 7*32768
#define CHUNKS ((NNZ + 255) / 256)

// edge packing: [31:18] = val as 14-bit fixed point, [17:0] = partner index
#define VSCALE 16383.f

// ---------------------------------------------------------------------------
// concat emb_u|emb_b -> x (fp16), accumulate l2 into out[1].
// grid-stride; ONE atomic per block.
// ---------------------------------------------------------------------------
__global__ __launch_bounds__(256) void concat_l2_kernel(
    const float* __restrict__ emb_u, const float* __restrict__ emb_b,
    __half* __restrict__ x, float* __restrict__ out) {
  const int total4 = (N_UB * D) / 4;
  const int nu4 = (NU * D) / 4;
  float sq = 0.f;
  for (int i = blockIdx.x * blockDim.x + threadIdx.x; i < total4;
       i += gridDim.x * blockDim.x) {
    float4 v = (i < nu4) ? ((const float4*)emb_u)[i]
                         : ((const float4*)emb_b)[i - nu4];
    sq += v.x * v.x + v.y * v.y + v.z * v.z + v.w * v.w;
    union { __half2 h[2]; int2 p; } u;
    u.h[0] = __floats2half2_rn(v.x, v.y);
    u.h[1] = __floats2half2_rn(v.z, v.w);
    ((int2*)x)[i] = u.p;
  }
  for (int off = 32; off; off >>= 1) sq += __shfl_down(sq, off);
  __shared__ float wsum[4];
  if ((threadIdx.x & 63) == 0) wsum[threadIdx.x >> 6] = sq;
  __syncthreads();
  if (threadIdx.x == 0) {
    float s = wsum[0] + wsum[1] + wsum[2] + wsum[3];
    atomicAdd(&out[1], s * (0.5f / (float)NU));
  }
}

// ---------------------------------------------------------------------------
// CSR build: histogram both sides
// ---------------------------------------------------------------------------
__global__ __launch_bounds__(256) void hist_kernel(
    const int* __restrict__ rows, const int* __restrict__ cols,
    int* __restrict__ cntr, int* __restrict__ cntc) {
  int e = blockIdx.x * blockDim.x + threadIdx.x;
  if (e >= NNZ) return;
  atomicAdd(&cntr[rows[e]], 1);
  atomicAdd(&cntc[cols[e]], 1);
}

__global__ __launch_bounds__(1024) void scan_block_kernel(
    const int* __restrict__ in, int* __restrict__ out, int* __restrict__ blktot,
    int n) {
  __shared__ int s[1024];
  int tid = threadIdx.x;
  int i = blockIdx.x * 1024 + tid;
  int v = (i < n) ? in[i] : 0;
  s[tid] = v;
  __syncthreads();
  for (int off = 1; off < 1024; off <<= 1) {
    int t = (tid >= off) ? s[tid - off] : 0;
    __syncthreads();
    s[tid] += t;
    __syncthreads();
  }
  if (i < n) out[i] = s[tid] - v;
  if (tid == 1023) blktot[blockIdx.x] = s[1023];
}

__global__ __launch_bounds__(1024) void scan_top_kernel(int* __restrict__ b,
                                                        int nb) {
  __shared__ int s[1024];
  int tid = threadIdx.x;
  int v = (tid < nb) ? b[tid] : 0;
  s[tid] = v;
  __syncthreads();
  for (int off = 1; off < 1024; off <<= 1) {
    int t = (tid >= off) ? s[tid - off] : 0;
    __syncthreads();
    s[tid] += t;
    __syncthreads();
  }
  if (tid < nb) b[tid] = s[tid] - v;
}

__global__ __launch_bounds__(1024) void add_off_kernel(
    int* __restrict__ out, const int* __restrict__ blktot, int* __restrict__ cur,
    int n, int total) {
  int i = blockIdx.x * 1024 + threadIdx.x;
  if (i < n) {
    int p = out[i] + blktot[blockIdx.x];
    out[i] = p;
    cur[i] = p;
  }
  if (i == 0) out[n] = total;
}

// ---------------------------------------------------------------------------
// binned scatter: sweep s handles destinations in [s*32768, (s+1)*32768).
// Confines each sweep's random writes to ~1.5 MB -> L2-resident lines.
// sweep derived from blockIdx (blocks dispatch roughly in order).
// ---------------------------------------------------------------------------
__global__ __launch_bounds__(256) void scatter_bin_kernel(
    const float* __restrict__ vals, const int* __restrict__ rows,
    const int* __restrict__ cols, int* __restrict__ curr, int* __restrict__ curc,
    unsigned* __restrict__ er, unsigned* __restrict__ ec) {
  int sweep = blockIdx.x / CHUNKS;
  int e = (blockIdx.x % CHUNKS) * 256 + threadIdx.x;
  if (e >= NNZ) return;
  int r = rows[e];
  int c = cols[e];
  bool dc = (c >> SBIN) == sweep;
  bool dr = (r >> SBIN) == sweep;
  if (dc | dr) {
    unsigned q = __float2uint_rn(vals[e] * VSCALE);
    if (dc) {
      int p = atomicAdd(&curc[c], 1);
      ec[p] = (q << 18) | (unsigned)r;
    }
    if (dr) {
      int p = atomicAdd(&curr[r], 1);
      er[p] = (q << 18) | (unsigned)c;
    }
  }
}

// ---------------------------------------------------------------------------
// pass 1 (CSR by col): y[c] = leaky(filt[c]) * sum val*x[src]
// 2 rows per wave: half-wave (32 lanes) per row, half2 (2 dims) per lane.
// ---------------------------------------------------------------------------
__global__ __launch_bounds__(256) void spmm_col_kernel(
    const int* __restrict__ ptrc, const unsigned* __restrict__ ec,
    const __half* __restrict__ x, const float* __restrict__ filt,
    __half* __restrict__ y) {
  int w = blockIdx.x * 4 + (threadIdx.x >> 6);
  int c = w * 2 + ((threadIdx.x >> 5) & 1);
  if (c >= N_IU) return;
  int sub = threadIdx.x & 31;
  int e = ptrc[c], e2 = ptrc[c + 1];
  float ax = 0.f, ay = 0.f;
  for (; e + 2 <= e2; e += 2) {
    unsigned p0 = ec[e], p1 = ec[e + 1];
    float2 x0 = __half22float2(
        *(const __half2*)&x[(size_t)(p0 & 0x3FFFFu) * D + 2 * sub]);
    float2 x1 = __half22float2(
        *(const __half2*)&x[(size_t)(p1 & 0x3FFFFu) * D + 2 * sub]);
    float v0 = (float)(p0 >> 18) * (1.f / VSCALE);
    float v1 = (float)(p1 >> 18) * (1.f / VSCALE);
    ax += v0 * x0.x + v1 * x1.x;
    ay += v0 * x0.y + v1 * x1.y;
  }
  if (e < e2) {
    unsigned p = ec[e];
    float2 xv = __half22float2(
        *(const __half2*)&x[(size_t)(p & 0x3FFFFu) * D + 2 * sub]);
    float v = (float)(p >> 18) * (1.f / VSCALE);
    ax += v * xv.x;
    ay += v * xv.y;
  }
  float fw = filt[c];
  float f = fw > 0.f ? fw : LEAKY * fw;
  *(__half2*)&y[(size_t)c * D + 2 * sub] = __floats2half2_rn(ax * f, ay * f);
}

// ---------------------------------------------------------------------------
// pass 2 (CSR by row): x[r] = sum val*y[src]
// ---------------------------------------------------------------------------
__global__ __launch_bounds__(256) void spmm_row_kernel(
    const int* __restrict__ ptrr, const unsigned* __restrict__ er,
    const __half* __restrict__ y, __half* __restrict__ x) {
  int w = blockIdx.x * 4 + (threadIdx.x >> 6);
  int r = w * 2 + ((threadIdx.x >> 5) & 1);
  if (r >= N_UB) return;
  int sub = threadIdx.x & 31;
  int e = ptrr[r], e2 = ptrr[r + 1];
  float ax = 0.f, ay = 0.f;
  for (; e + 2 <= e2; e += 2) {
    unsigned p0 = er[e], p1 = er[e + 1];
    float2 y0 = __half22float2(
        *(const __half2*)&y[(size_t)(p0 & 0x3FFFFu) * D + 2 * sub]);
    float2 y1 = __half22float2(
        *(const __half2*)&y[(size_t)(p1 & 0x3FFFFu) * D + 2 * sub]);
    float v0 = (float)(p0 >> 18) * (1.f / VSCALE);
    float v1 = (float)(p1 >> 18) * (1.f / VSCALE);
    ax += v0 * y0.x + v1 * y1.x;
    ay += v0 * y0.y + v1 * y1.y;
  }
  if (e < e2) {
    unsigned p = er[e];
    float2 yv = __half22float2(
        *(const __half2*)&y[(size_t)(p & 0x3FFFFu) * D + 2 * sub]);
    float v = (float)(p >> 18) * (1.f / VSCALE);
    ax += v * yv.x;
    ay += v * yv.y;
  }
  *(__half2*)&x[(size_t)r * D + 2 * sub] = __floats2half2_rn(ax, ay);
}

// ---------------------------------------------------------------------------
// last layer pass 2 ONLY at gathered rows, accumulated into uacc/bacc (fp32)
// ---------------------------------------------------------------------------
__global__ __launch_bounds__(256) void spmm_gather_last_kernel(
    const int* __restrict__ ptrr, const unsigned* __restrict__ er,
    const __half* __restrict__ y, const int* __restrict__ u_idx,
    const int* __restrict__ b_idx, float* __restrict__ uacc,
    float* __restrict__ bacc) {
  int w = blockIdx.x * 4 + (threadIdx.x >> 6);
  int i = w * 2 + ((threadIdx.x >> 5) & 1);
  if (i >= 3 * BATCH) return;
  int sub = threadIdx.x & 31;
  int row;
  float* dst;
  if (i < BATCH) {
    row = u_idx[i];
    dst = &uacc[(size_t)i * D];
  } else {
    int j = i - BATCH;
    row = NU + b_idx[j];
    dst = &bacc[(size_t)j * D];
  }
  int e = ptrr[row], e2 = ptrr[row + 1];
  float ax = 0.f, ay = 0.f;
  for (; e + 2 <= e2; e += 2) {
    unsigned p0 = er[e], p1 = er[e + 1];
    float2 y0 = __half22float2(
        *(const __half2*)&y[(size_t)(p0 & 0x3FFFFu) * D + 2 * sub]);
    float2 y1 = __half22float2(
        *(const __half2*)&y[(size_t)(p1 & 0x3FFFFu) * D + 2 * sub]);
    float v0 = (float)(p0 >> 18) * (1.f / VSCALE);
    float v1 = (float)(p1 >> 18) * (1.f / VSCALE);
    ax += v0 * y0.x + v1 * y1.x;
    ay += v0 * y0.y + v1 * y1.y;
  }
  if (e < e2) {
    unsigned p = er[e];
    float2 yv = __half22float2(
        *(const __half2*)&y[(size_t)(p & 0x3FFFFu) * D + 2 * sub]);
    float v = (float)(p >> 18) * (1.f / VSCALE);
    ax += v * yv.x;
    ay += v * yv.y;
  }
  float2* dp = (float2*)&dst[2 * sub];
  float2 d = *dp;
  d.x += ax;
  d.y += ay;
  *dp = d;
}

// ---------------------------------------------------------------------------
// gather-accumulate (intermediate layers): uacc/bacc += x[idx] (fp16 -> fp32)
// ---------------------------------------------------------------------------
__global__ __launch_bounds__(256) void gather_acc_kernel(
    const __half* __restrict__ x, const int* __restrict__ u_idx,
    const int* __restrict__ b_idx, float* __restrict__ uacc,
    float* __restrict__ bacc) {
  int w = blockIdx.x * 4 + (threadIdx.x >> 6);
  int i = w * 2 + ((threadIdx.x >> 5) & 1);
  if (i >= 3 * BATCH) return;
  int sub = threadIdx.x & 31;
  int src;
  float* dst;
  if (i < BATCH) {
    src = u_idx[i];
    dst = &uacc[(size_t)i * D];
  } else {
    int j = i - BATCH;
    src = NU + b_idx[j];
    dst = &bacc[(size_t)j * D];
  }
  float2 xf =
      __half22float2(*(const __half2*)&x[(size_t)src * D + 2 * sub]);
  float2* dp = (float2*)&dst[2 * sub];
  float2 d = *dp;
  d.x += xf.x;
  d.y += xf.y;
  *dp = d;
}

// ---------------------------------------------------------------------------
// loss: z = dot(u, b1-b0)/16; loss = mean softplus(z). half-wave per elem.
// ---------------------------------------------------------------------------
__global__ __launch_bounds__(256) void loss_kernel(
    const float* __restrict__ uacc, const float* __restrict__ bacc,
    float* __restrict__ out) {
  int w = blockIdx.x * 4 + (threadIdx.x >> 6);
  int i = w * 2 + ((threadIdx.x >> 5) & 1);
  if (i >= BATCH) return;
  int sub = threadIdx.x & 31;
  float2 u = *(const float2*)&uacc[(size_t)i * D + 2 * sub];
  float2 b0 = *(const float2*)&bacc[(size_t)(2 * i) * D + 2 * sub];
  float2 b1 = *(const float2*)&bacc[(size_t)(2 * i + 1) * D + 2 * sub];
  float t = (u.x * (b1.x - b0.x) + u.y * (b1.y - b0.y)) * (1.f / 16.f);
  for (int off = 16; off; off >>= 1) t += __shfl_down(t, off, 32);
  if (sub == 0) {
    float z = t;
    float sp = z > 0.f ? z + log1pf(expf(-z)) : log1pf(expf(z));
    atomicAdd(&out[0], sp * (1.f / (float)BATCH));
  }
}

extern "C" void kernel_launch(void* const* d_in, const int* in_sizes, int n_in,
                              void* d_out, int out_size, void* d_ws,
                              size_t ws_size, hipStream_t stream) {
  const float* emb_u = (const float*)d_in[0];
  const float* emb_b = (const float*)d_in[1];
  const float* filter_w = (const float*)d_in[2];
  const float* vals = (const float*)d_in[3];
  const int* rows = (const int*)d_in[4];
  const int* cols = (const int*)d_in[5];
  const int* u_idx = (const int*)d_in[6];
  const int* b_idx = (const int*)d_in[7];
  float* out = (float*)d_out;

  // workspace layout
  __half* xA = (__half*)d_ws;                          // N_UB*D halves
  __half* yH = xA + (size_t)N_UB * D;                  // N_IU*D halves
  float* uacc = (float*)(yH + (size_t)N_IU * D);       // BATCH*D
  float* bacc = uacc + (size_t)BATCH * D;              // 2*BATCH*D
  unsigned* ec = (unsigned*)(bacc + (size_t)2 * BATCH * D);  // NNZ
  unsigned* er = ec + NNZ;                             // NNZ
  int* ptrc = (int*)(er + NNZ);                        // N_IU+1
  int* ptrr = ptrc + (N_IU + 1);                       // N_UB+1
  int* curc = ptrr + (N_UB + 1);                       // N_IU
  int* curr = curc + N_IU;                             // N_UB
  int* blktot = curr + N_UB;                           // 1024

  hipMemsetAsync(out, 0, 2 * sizeof(float), stream);
  hipMemsetAsync(uacc, 0, (size_t)3 * BATCH * D * sizeof(float), stream);
  hipMemsetAsync(curc, 0, (size_t)N_IU * sizeof(int), stream);
  hipMemsetAsync(curr, 0, (size_t)N_UB * sizeof(int), stream);

  concat_l2_kernel<<<1024, 256, 0, stream>>>(emb_u, emb_b, xA, out);
  gather_acc_kernel<<<(3 * BATCH + 7) / 8, 256, 0, stream>>>(xA, u_idx, b_idx,
                                                             uacc, bacc);

  // ---- build CSRs ----
  hist_kernel<<<(NNZ + 255) / 256, 256, 0, stream>>>(rows, cols, curr, curc);
  {
    int nb = (N_IU + 1023) / 1024;
    scan_block_kernel<<<nb, 1024, 0, stream>>>(curc, ptrc, blktot, N_IU);
    scan_top_kernel<<<1, 1024, 0, stream>>>(blktot, nb);
    add_off_kernel<<<nb, 1024, 0, stream>>>(ptrc, blktot, curc, N_IU, NNZ);
  }
  {
    int nb = (N_UB + 1023) / 1024;
    scan_block_kernel<<<nb, 1024, 0, stream>>>(curr, ptrr, blktot, N_UB);
    scan_top_kernel<<<1, 1024, 0, stream>>>(blktot, nb);
    add_off_kernel<<<nb, 1024, 0, stream>>>(ptrr, blktot, curr, N_UB, NNZ);
  }
  scatter_bin_kernel<<<NSWEEP * CHUNKS, 256, 0, stream>>>(vals, rows, cols,
                                                          curr, curc, er, ec);

  // ---- 3 layers ----
  for (int l = 0; l < NLAYER; ++l) {
    spmm_col_kernel<<<(N_IU + 7) / 8, 256, 0, stream>>>(
        ptrc, ec, xA, filter_w + (size_t)l * N_IU, yH);
    if (l < NLAYER - 1) {
      spmm_row_kernel<<<(N_UB + 7) / 8, 256, 0, stream>>>(ptrr, er, yH, xA);
      gather_acc_kernel<<<(3 * BATCH + 7) / 8, 256, 0, stream>>>(
          xA, u_idx, b_idx, uacc, bacc);
    } else {
      spmm_gather_last_kernel<<<(3 * BATCH + 7) / 8, 256, 0, stream>>>(
          ptrr, er, yH, u_idx, b_idx, uacc, bacc);
    }
  }

  loss_kernel<<<(BATCH + 7) / 8, 256, 0, stream>>>(uacc, bacc, out);
}

// Round 4
// 725.798 us; speedup vs baseline: 4.5086x; 1.2130x over previous
//
#include <hip/hip_runtime.h>
#include <hip/hip_fp16.h>
#include <math.h>

#define NU 100000
#define NB 50000
#define NI 100000
#define D 64
#define NLAYER 3
#define NNZ 2000000
#define BATCH 8192
#define LEAKY 0.2f
#define N_UB (NU + NB)   // 150000
#define N_IU (NI + NU)   // 200000

#define CHUNKS ((NNZ + 255) / 256)
#define NSWEEP 7
#define ERBIN 22000      // 7*22000 >= 150000

// rk packing: [31:18] q (14-bit val), [17:9] rank_r, [8:0] rank_c
#define VSCALE 16383.f

// ---------------------------------------------------------------------------
// concat emb_u|emb_b -> x (fp16), accumulate l2 into out[1]
// ---------------------------------------------------------------------------
__global__ __launch_bounds__(256) void concat_l2_kernel(
    const float* __restrict__ emb_u, const float* __restrict__ emb_b,
    __half* __restrict__ x, float* __restrict__ out) {
  const int total4 = (N_UB * D) / 4;
  const int nu4 = (NU * D) / 4;
  float sq = 0.f;
  for (int i = blockIdx.x * blockDim.x + threadIdx.x; i < total4;
       i += gridDim.x * blockDim.x) {
    float4 v = (i < nu4) ? ((const float4*)emb_u)[i]
                         : ((const float4*)emb_b)[i - nu4];
    sq += v.x * v.x + v.y * v.y + v.z * v.z + v.w * v.w;
    union { __half2 h[2]; int2 p; } u;
    u.h[0] = __floats2half2_rn(v.x, v.y);
    u.h[1] = __floats2half2_rn(v.z, v.w);
    ((int2*)x)[i] = u.p;
  }
  for (int off = 32; off; off >>= 1) sq += __shfl_down(sq, off);
  __shared__ float wsum[4];
  if ((threadIdx.x & 63) == 0) wsum[threadIdx.x >> 6] = sq;
  __syncthreads();
  if (threadIdx.x == 0) {
    float s = wsum[0] + wsum[1] + wsum[2] + wsum[3];
    atomicAdd(&out[1], s * (0.5f / (float)NU));
  }
}

// ---------------------------------------------------------------------------
// rank pass: one atomic per (edge,side); rank = old count. Also quantize val.
// rk[e] = q<<18 | rank_r<<9 | rank_c
// ---------------------------------------------------------------------------
__global__ __launch_bounds__(256) void rank_kernel(
    const int* __restrict__ rows, const int* __restrict__ cols,
    const float* __restrict__ vals, int* __restrict__ cntr,
    int* __restrict__ cntc, unsigned* __restrict__ rk) {
  int e = blockIdx.x * blockDim.x + threadIdx.x;
  if (e >= NNZ) return;
  unsigned rc = (unsigned)atomicAdd(&cntc[cols[e]], 1);
  unsigned rr = (unsigned)atomicAdd(&cntr[rows[e]], 1);
  unsigned q = __float2uint_rn(vals[e] * VSCALE);
  rk[e] = (q << 18) | (rr << 9) | rc;
}

// ---------------------------------------------------------------------------
// scans (ptr = exclusive prefix of counts)
// ---------------------------------------------------------------------------
__global__ __launch_bounds__(1024) void scan_block_kernel(
    const int* __restrict__ in, int* __restrict__ out, int* __restrict__ blktot,
    int n) {
  __shared__ int s[1024];
  int tid = threadIdx.x;
  int i = blockIdx.x * 1024 + tid;
  int v = (i < n) ? in[i] : 0;
  s[tid] = v;
  __syncthreads();
  for (int off = 1; off < 1024; off <<= 1) {
    int t = (tid >= off) ? s[tid - off] : 0;
    __syncthreads();
    s[tid] += t;
    __syncthreads();
  }
  if (i < n) out[i] = s[tid] - v;
  if (tid == 1023) blktot[blockIdx.x] = s[1023];
}

__global__ __launch_bounds__(1024) void scan_top_kernel(int* __restrict__ b,
                                                        int nb) {
  __shared__ int s[1024];
  int tid = threadIdx.x;
  int v = (tid < nb) ? b[tid] : 0;
  s[tid] = v;
  __syncthreads();
  for (int off = 1; off < 1024; off <<= 1) {
    int t = (tid >= off) ? s[tid - off] : 0;
    __syncthreads();
    s[tid] += t;
    __syncthreads();
  }
  if (tid < nb) b[tid] = s[tid] - v;
}

__global__ __launch_bounds__(1024) void add_off_kernel(
    int* __restrict__ out, const int* __restrict__ blktot, int n, int total) {
  int i = blockIdx.x * 1024 + threadIdx.x;
  if (i < n) out[i] += blktot[blockIdx.x];
  if (i == 0) out[n] = total;
}

// ---------------------------------------------------------------------------
// atomic-free binned scatter: position = ptr[dst] + rank.
// sweep confines each array's writes to an L2-resident region.
// ---------------------------------------------------------------------------
__global__ __launch_bounds__(256) void scatter_sweep_kernel(
    const int* __restrict__ rows, const int* __restrict__ cols,
    const unsigned* __restrict__ rk, const int* __restrict__ ptrr,
    const int* __restrict__ ptrc, unsigned* __restrict__ er,
    unsigned* __restrict__ ec) {
  int sweep = blockIdx.x / CHUNKS;
  int e = (blockIdx.x % CHUNKS) * 256 + threadIdx.x;
  if (e >= NNZ) return;
  int r = rows[e];
  int c = cols[e];
  unsigned k = rk[e];
  unsigned q = k >> 18;
  if ((c >> 15) == sweep) {
    unsigned rc = k & 0x1FFu;
    ec[ptrc[c] + rc] = (q << 18) | (unsigned)r;
  }
  if (r / ERBIN == sweep) {
    unsigned rr = (k >> 9) & 0x1FFu;
    er[ptrr[r] + rr] = (q << 18) | (unsigned)c;
  }
}

// ---------------------------------------------------------------------------
// pass 1 (CSR by col): y[c] = leaky(filt[c]) * sum val*x[src]
// half-wave per row, half2 per lane; unroll 4; NT loads on edge stream.
// ---------------------------------------------------------------------------
__global__ __launch_bounds__(256) void spmm_col_kernel(
    const int* __restrict__ ptrc, const unsigned* __restrict__ ec,
    const __half* __restrict__ x, const float* __restrict__ filt,
    __half* __restrict__ y) {
  int w = blockIdx.x * 4 + (threadIdx.x >> 6);
  int c = w * 2 + ((threadIdx.x >> 5) & 1);
  if (c >= N_IU) return;
  int sub = threadIdx.x & 31;
  int e = ptrc[c], e2 = ptrc[c + 1];
  float ax = 0.f, ay = 0.f;
  for (; e + 4 <= e2; e += 4) {
    unsigned p0 = __builtin_nontemporal_load(&ec[e]);
    unsigned p1 = __builtin_nontemporal_load(&ec[e + 1]);
    unsigned p2 = __builtin_nontemporal_load(&ec[e + 2]);
    unsigned p3 = __builtin_nontemporal_load(&ec[e + 3]);
    float2 x0 = __half22float2(
        *(const __half2*)&x[(size_t)(p0 & 0x3FFFFu) * D + 2 * sub]);
    float2 x1 = __half22float2(
        *(const __half2*)&x[(size_t)(p1 & 0x3FFFFu) * D + 2 * sub]);
    float2 x2 = __half22float2(
        *(const __half2*)&x[(size_t)(p2 & 0x3FFFFu) * D + 2 * sub]);
    float2 x3 = __half22float2(
        *(const __half2*)&x[(size_t)(p3 & 0x3FFFFu) * D + 2 * sub]);
    float v0 = (float)(p0 >> 18), v1 = (float)(p1 >> 18);
    float v2 = (float)(p2 >> 18), v3 = (float)(p3 >> 18);
    ax += v0 * x0.x + v1 * x1.x + v2 * x2.x + v3 * x3.x;
    ay += v0 * x0.y + v1 * x1.y + v2 * x2.y + v3 * x3.y;
  }
  for (; e < e2; ++e) {
    unsigned p = __builtin_nontemporal_load(&ec[e]);
    float2 xv = __half22float2(
        *(const __half2*)&x[(size_t)(p & 0x3FFFFu) * D + 2 * sub]);
    float v = (float)(p >> 18);
    ax += v * xv.x;
    ay += v * xv.y;
  }
  float fw = filt[c];
  float f = (fw > 0.f ? fw : LEAKY * fw) * (1.f / VSCALE);
  *(__half2*)&y[(size_t)c * D + 2 * sub] = __floats2half2_rn(ax * f, ay * f);
}

// ---------------------------------------------------------------------------
// pass 2 (CSR by row): x[r] = sum val*y[src]
// ---------------------------------------------------------------------------
__global__ __launch_bounds__(256) void spmm_row_kernel(
    const int* __restrict__ ptrr, const unsigned* __restrict__ er,
    const __half* __restrict__ y, __half* __restrict__ x) {
  int w = blockIdx.x * 4 + (threadIdx.x >> 6);
  int r = w * 2 + ((threadIdx.x >> 5) & 1);
  if (r >= N_UB) return;
  int sub = threadIdx.x & 31;
  int e = ptrr[r], e2 = ptrr[r + 1];
  float ax = 0.f, ay = 0.f;
  for (; e + 4 <= e2; e += 4) {
    unsigned p0 = __builtin_nontemporal_load(&er[e]);
    unsigned p1 = __builtin_nontemporal_load(&er[e + 1]);
    unsigned p2 = __builtin_nontemporal_load(&er[e + 2]);
    unsigned p3 = __builtin_nontemporal_load(&er[e + 3]);
    float2 y0 = __half22float2(
        *(const __half2*)&y[(size_t)(p0 & 0x3FFFFu) * D + 2 * sub]);
    float2 y1 = __half22float2(
        *(const __half2*)&y[(size_t)(p1 & 0x3FFFFu) * D + 2 * sub]);
    float2 y2 = __half22float2(
        *(const __half2*)&y[(size_t)(p2 & 0x3FFFFu) * D + 2 * sub]);
    float2 y3 = __half22float2(
        *(const __half2*)&y[(size_t)(p3 & 0x3FFFFu) * D + 2 * sub]);
    float v0 = (float)(p0 >> 18), v1 = (float)(p1 >> 18);
    float v2 = (float)(p2 >> 18), v3 = (float)(p3 >> 18);
    ax += v0 * y0.x + v1 * y1.x + v2 * y2.x + v3 * y3.x;
    ay += v0 * y0.y + v1 * y1.y + v2 * y2.y + v3 * y3.y;
  }
  for (; e < e2; ++e) {
    unsigned p = __builtin_nontemporal_load(&er[e]);
    float2 yv = __half22float2(
        *(const __half2*)&y[(size_t)(p & 0x3FFFFu) * D + 2 * sub]);
    float v = (float)(p >> 18);
    ax += v * yv.x;
    ay += v * yv.y;
  }
  *(__half2*)&x[(size_t)r * D + 2 * sub] =
      __floats2half2_rn(ax * (1.f / VSCALE), ay * (1.f / VSCALE));
}

// ---------------------------------------------------------------------------
// last layer pass 2 ONLY at gathered rows, accumulated into uacc/bacc (fp32)
// ---------------------------------------------------------------------------
__global__ __launch_bounds__(256) void spmm_gather_last_kernel(
    const int* __restrict__ ptrr, const unsigned* __restrict__ er,
    const __half* __restrict__ y, const int* __restrict__ u_idx,
    const int* __restrict__ b_idx, float* __restrict__ uacc,
    float* __restrict__ bacc) {
  int w = blockIdx.x * 4 + (threadIdx.x >> 6);
  int i = w * 2 + ((threadIdx.x >> 5) & 1);
  if (i >= 3 * BATCH) return;
  int sub = threadIdx.x & 31;
  int row;
  float* dst;
  if (i < BATCH) {
    row = u_idx[i];
    dst = &uacc[(size_t)i * D];
  } else {
    int j = i - BATCH;
    row = NU + b_idx[j];
    dst = &bacc[(size_t)j * D];
  }
  int e = ptrr[row], e2 = ptrr[row + 1];
  float ax = 0.f, ay = 0.f;
  for (; e + 2 <= e2; e += 2) {
    unsigned p0 = er[e], p1 = er[e + 1];
    float2 y0 = __half22float2(
        *(const __half2*)&y[(size_t)(p0 & 0x3FFFFu) * D + 2 * sub]);
    float2 y1 = __half22float2(
        *(const __half2*)&y[(size_t)(p1 & 0x3FFFFu) * D + 2 * sub]);
    float v0 = (float)(p0 >> 18), v1 = (float)(p1 >> 18);
    ax += v0 * y0.x + v1 * y1.x;
    ay += v0 * y0.y + v1 * y1.y;
  }
  if (e < e2) {
    unsigned p = er[e];
    float2 yv = __half22float2(
        *(const __half2*)&y[(size_t)(p & 0x3FFFFu) * D + 2 * sub]);
    float v = (float)(p >> 18);
    ax += v * yv.x;
    ay += v * yv.y;
  }
  float2* dp = (float2*)&dst[2 * sub];
  float2 d = *dp;
  d.x += ax * (1.f / VSCALE);
  d.y += ay * (1.f / VSCALE);
  *dp = d;
}

// ---------------------------------------------------------------------------
// gather-accumulate (intermediate layers)
// ---------------------------------------------------------------------------
__global__ __launch_bounds__(256) void gather_acc_kernel(
    const __half* __restrict__ x, const int* __restrict__ u_idx,
    const int* __restrict__ b_idx, float* __restrict__ uacc,
    float* __restrict__ bacc) {
  int w = blockIdx.x * 4 + (threadIdx.x >> 6);
  int i = w * 2 + ((threadIdx.x >> 5) & 1);
  if (i >= 3 * BATCH) return;
  int sub = threadIdx.x & 31;
  int src;
  float* dst;
  if (i < BATCH) {
    src = u_idx[i];
    dst = &uacc[(size_t)i * D];
  } else {
    int j = i - BATCH;
    src = NU + b_idx[j];
    dst = &bacc[(size_t)j * D];
  }
  float2 xf =
      __half22float2(*(const __half2*)&x[(size_t)src * D + 2 * sub]);
  float2* dp = (float2*)&dst[2 * sub];
  float2 d = *dp;
  d.x += xf.x;
  d.y += xf.y;
  *dp = d;
}

// ---------------------------------------------------------------------------
// loss
// ---------------------------------------------------------------------------
__global__ __launch_bounds__(256) void loss_kernel(
    const float* __restrict__ uacc, const float* __restrict__ bacc,
    float* __restrict__ out) {
  int w = blockIdx.x * 4 + (threadIdx.x >> 6);
  int i = w * 2 + ((threadIdx.x >> 5) & 1);
  if (i >= BATCH) return;
  int sub = threadIdx.x & 31;
  float2 u = *(const float2*)&uacc[(size_t)i * D + 2 * sub];
  float2 b0 = *(const float2*)&bacc[(size_t)(2 * i) * D + 2 * sub];
  float2 b1 = *(const float2*)&bacc[(size_t)(2 * i + 1) * D + 2 * sub];
  float t = (u.x * (b1.x - b0.x) + u.y * (b1.y - b0.y)) * (1.f / 16.f);
  for (int off = 16; off; off >>= 1) t += __shfl_down(t, off, 32);
  if (sub == 0) {
    float z = t;
    float sp = z > 0.f ? z + log1pf(expf(-z)) : log1pf(expf(z));
    atomicAdd(&out[0], sp * (1.f / (float)BATCH));
  }
}

extern "C" void kernel_launch(void* const* d_in, const int* in_sizes, int n_in,
                              void* d_out, int out_size, void* d_ws,
                              size_t ws_size, hipStream_t stream) {
  const float* emb_u = (const float*)d_in[0];
  const float* emb_b = (const float*)d_in[1];
  const float* filter_w = (const float*)d_in[2];
  const float* vals = (const float*)d_in[3];
  const int* rows = (const int*)d_in[4];
  const int* cols = (const int*)d_in[5];
  const int* u_idx = (const int*)d_in[6];
  const int* b_idx = (const int*)d_in[7];
  float* out = (float*)d_out;

  // workspace layout
  __half* xA = (__half*)d_ws;                          // N_UB*D halves
  __half* yH = xA + (size_t)N_UB * D;                  // N_IU*D halves
  float* uacc = (float*)(yH + (size_t)N_IU * D);       // BATCH*D
  float* bacc = uacc + (size_t)BATCH * D;              // 2*BATCH*D
  unsigned* ec = (unsigned*)(bacc + (size_t)2 * BATCH * D);  // NNZ
  unsigned* er = ec + NNZ;                             // NNZ
  unsigned* rk = er + NNZ;                             // NNZ
  int* ptrc = (int*)(rk + NNZ);                        // N_IU+1
  int* ptrr = ptrc + (N_IU + 1);                       // N_UB+1
  int* cntc = ptrr + (N_UB + 1);                       // N_IU
  int* cntr = cntc + N_IU;                             // N_UB
  int* blktot = cntr + N_UB;                           // 1024

  hipMemsetAsync(out, 0, 2 * sizeof(float), stream);
  hipMemsetAsync(uacc, 0, (size_t)3 * BATCH * D * sizeof(float), stream);
  hipMemsetAsync(cntc, 0, (size_t)(N_IU + N_UB) * sizeof(int), stream);

  concat_l2_kernel<<<1024, 256, 0, stream>>>(emb_u, emb_b, xA, out);
  gather_acc_kernel<<<(3 * BATCH + 7) / 8, 256, 0, stream>>>(xA, u_idx, b_idx,
                                                             uacc, bacc);

  // ---- build CSRs: ranks -> scans -> atomic-free binned scatter ----
  rank_kernel<<<(NNZ + 255) / 256, 256, 0, stream>>>(rows, cols, vals, cntr,
                                                     cntc, rk);
  {
    int nb = (N_IU + 1023) / 1024;
    scan_block_kernel<<<nb, 1024, 0, stream>>>(cntc, ptrc, blktot, N_IU);
    scan_top_kernel<<<1, 1024, 0, stream>>>(blktot, nb);
    add_off_kernel<<<nb, 1024, 0, stream>>>(ptrc, blktot, N_IU, NNZ);
  }
  {
    int nb = (N_UB + 1023) / 1024;
    scan_block_kernel<<<nb, 1024, 0, stream>>>(cntr, ptrr, blktot, N_UB);
    scan_top_kernel<<<1, 1024, 0, stream>>>(blktot, nb);
    add_off_kernel<<<nb, 1024, 0, stream>>>(ptrr, blktot, N_UB, NNZ);
  }
  scatter_sweep_kernel<<<NSWEEP * CHUNKS, 256, 0, stream>>>(rows, cols, rk,
                                                            ptrr, ptrc, er, ec);

  // ---- 3 layers ----
  for (int l = 0; l < NLAYER; ++l) {
    spmm_col_kernel<<<(N_IU + 7) / 8, 256, 0, stream>>>(
        ptrc, ec, xA, filter_w + (size_t)l * N_IU, yH);
    if (l < NLAYER - 1) {
      spmm_row_kernel<<<(N_UB + 7) / 8, 256, 0, stream>>>(ptrr, er, yH, xA);
      gather_acc_kernel<<<(3 * BATCH + 7) / 8, 256, 0, stream>>>(
          xA, u_idx, b_idx, uacc, bacc);
    } else {
      spmm_gather_last_kernel<<<(3 * BATCH + 7) / 8, 256, 0, stream>>>(
          ptrr, er, yH, u_idx, b_idx, uacc, bacc);
    }
  }

  loss_kernel<<<(BATCH + 7) / 8, 256, 0, stream>>>(uacc, bacc, out);
}